// Round 10
// baseline (40.807 us; speedup 1.0000x reference)
//
#include <hip/hip_runtime.h>
#include <cstdint>
#include <cstddef>

#define ROWS 16384
#define COLS 1024

typedef float f32x2 __attribute__((ext_vector_type(2)));

// rotl via single v_alignbit_b32: alignbit(x,x,32-r) = (x>>(32-r))|(x<<r)
__device__ __forceinline__ uint32_t rotl32(uint32_t x, int r) {
    return __builtin_amdgcn_alignbit(x, x, 32 - r);
}

// Four Threefry-2x32 states in lockstep.
struct TF4 { uint32_t a0,a1,b0,b1,c0,c1,d0,d1; };

__device__ __forceinline__ void tf_round4(TF4& s, int r) {
    s.a0 += s.a1; s.b0 += s.b1; s.c0 += s.c1; s.d0 += s.d1;
    s.a1 = rotl32(s.a1, r) ^ s.a0;
    s.b1 = rotl32(s.b1, r) ^ s.b0;
    s.c1 = rotl32(s.c1, r) ^ s.c0;
    s.d1 = rotl32(s.d1, r) ^ s.d0;
}

// Round with the preceding x0-injection folded: x0 = x0 + x1 + k (v_add3).
__device__ __forceinline__ void tf_round4_k(TF4& s, int r, uint32_t k) {
    s.a0 = s.a0 + s.a1 + k; s.b0 = s.b0 + s.b1 + k;
    s.c0 = s.c0 + s.c1 + k; s.d0 = s.d0 + s.d1 + k;
    s.a1 = rotl32(s.a1, r) ^ s.a0;
    s.b1 = rotl32(s.b1, r) ^ s.b0;
    s.c1 = rotl32(s.c1, r) ^ s.c0;
    s.d1 = rotl32(s.d1, r) ^ s.d0;
}

__device__ __forceinline__ void inj4_x1(TF4& s, uint32_t k1) {  // x1 += k only
    s.a1 += k1; s.b1 += k1; s.c1 += k1; s.d1 += k1;
}

// Threefry-2x32-20, key (0,42), counters (0, i..i+3), bits = o0 ^ o1.
__device__ __forceinline__ uint4 threefry_bits4(uint32_t i, uint32_t ks2_s) {
    const uint32_t ks1 = 42u;
    const uint32_t ks2 = 0x1BD11BF0u;   // 0x1BD11BDA ^ 0 ^ 42

    TF4 s;
    s.a1 = i + 42u;  s.a0 = s.a1;       // x0 = 0 + x1 after round-1 add
    s.b1 = i + 43u;  s.b0 = s.b1;
    s.c1 = i + 44u;  s.c0 = s.c1;
    s.d1 = i + 45u;  s.d0 = s.d1;
    s.a1 = rotl32(s.a1, 13) ^ s.a0;     // round-1 tail
    s.b1 = rotl32(s.b1, 13) ^ s.b0;
    s.c1 = rotl32(s.c1, 13) ^ s.c0;
    s.d1 = rotl32(s.d1, 13) ^ s.d0;
    tf_round4(s, 15); tf_round4(s, 26); tf_round4(s, 6);
    inj4_x1(s, ks2 + 1u);
    tf_round4_k(s, 17, ks1);
    tf_round4(s, 29); tf_round4(s, 16); tf_round4(s, 24);
    inj4_x1(s, 2u);
    tf_round4_k(s, 13, ks2_s);
    tf_round4(s, 15); tf_round4(s, 26); tf_round4(s, 6);
    inj4_x1(s, ks1 + 3u);
    tf_round4(s, 17); tf_round4(s, 29); tf_round4(s, 16); tf_round4(s, 24);
    inj4_x1(s, ks2 + 4u);
    tf_round4_k(s, 13, ks1);
    tf_round4(s, 15); tf_round4(s, 26); tf_round4(s, 6);
    s.a0 += ks2; s.b0 += ks2; s.c0 += ks2; s.d0 += ks2;
    s.a1 += 5u;  s.b1 += 5u;  s.c1 += 5u;  s.d1 += 5u;

    return make_uint4(s.a0 ^ s.a1, s.b0 ^ s.b1, s.c0 ^ s.c1, s.d0 ^ s.d1);
}

// Rare tail (L <= -7.2134752 i.e. w >= 5, ~0.33%/lane): Giles upper branch,
// coefficients pre-scaled by 1.1*sqrt(2). Takes L = log2(1 - v^2).
__device__ __noinline__ float noise_tail(float L) {
    float w = -0.69314718f * L;
    float s = __builtin_amdgcn_sqrtf(w) - 3.0f;
    float q = -3.1146030e-04f;
    q = fmaf(q, s, 1.5704224e-04f);
    q = fmaf(q, s, 2.0990855e-03f);
    q = fmaf(q, s, -5.7144932e-03f);
    q = fmaf(q, s, 8.9285939e-03f);
    q = fmaf(q, s, -1.1857797e-02f);
    q = fmaf(q, s, 1.4683435e-02f);
    q = fmaf(q, s, 1.5582439e+00f);
    q = fmaf(q, s, 4.4070777e+00f);
    return q;
}

struct NoisePair { f32x2 lo, hi; };

// 4 elements; float pipeline in packed f32x2 (v_pk_fma_f32 / v_pk_mul_f32),
// bit-identical per component. Central poly: Giles coeffs pre-scaled by
// 1.1*sqrt2, re-centered in L = log2(1-v^2).
__device__ __forceinline__ NoisePair noise4(uint32_t idx0, uint32_t ks2_s) {
    uint4 b = threefry_bits4(idx0, ks2_s);

    f32x2 f01 = { (float)(b.x >> 9), (float)(b.y >> 9) };
    f32x2 f23 = { (float)(b.z >> 9), (float)(b.w >> 9) };

    const f32x2 S  = { 2.3841858e-07f, 2.3841858e-07f };   // 2^-22
    const f32x2 M  = { -0.99999994f, -0.99999994f };
    const f32x2 ONE = { 1.0f, 1.0f };

    f32x2 v01 = __builtin_elementwise_fma(f01, S, M);
    f32x2 v23 = __builtin_elementwise_fma(f23, S, M);

    f32x2 t01 = __builtin_elementwise_fma(-v01, v01, ONE);
    f32x2 t23 = __builtin_elementwise_fma(-v23, v23, ONE);

    f32x2 L01 = { __log2f(t01.x), __log2f(t01.y) };
    f32x2 L23 = { __log2f(t23.x), __log2f(t23.y) };

    const f32x2 K4 = { 7.84913e-05f, 7.84913e-05f };
    const f32x2 K3 = { 1.781908e-03f, 1.781908e-03f };
    const f32x2 K2 = { 1.0031874e-02f, 1.0031874e-02f };
    const f32x2 K1 = { -2.4839395e-01f, -2.4839395e-01f };
    const f32x2 K0 = { 1.3795727e+00f, 1.3795727e+00f };

    f32x2 p01 = __builtin_elementwise_fma(K4, L01, K3);
    f32x2 p23 = __builtin_elementwise_fma(K4, L23, K3);
    p01 = __builtin_elementwise_fma(p01, L01, K2);
    p23 = __builtin_elementwise_fma(p23, L23, K2);
    p01 = __builtin_elementwise_fma(p01, L01, K1);
    p23 = __builtin_elementwise_fma(p23, L23, K1);
    p01 = __builtin_elementwise_fma(p01, L01, K0);
    p23 = __builtin_elementwise_fma(p23, L23, K0);

    NoisePair n;
    n.lo = p01 * v01;
    n.hi = p23 * v23;

    const float THR = -7.2134752f;
    if (L01.x <= THR) n.lo.x = noise_tail(L01.x) * v01.x;
    if (L01.y <= THR) n.lo.y = noise_tail(L01.y) * v01.y;
    if (L23.x <= THR) n.hi.x = noise_tail(L23.x) * v23.x;
    if (L23.y <= THR) n.hi.y = noise_tail(L23.y) * v23.y;
    return n;
}

// One WAVE per row (64 lanes x 16 elems); 4 rows per 256-thread block.
__global__ void __launch_bounds__(256, 8)
gaussian_dp_kernel(const float* __restrict__ in, float* __restrict__ out) {
    const int wid  = threadIdx.x >> 6;
    const int lane = threadIdx.x & 63;
    const int r    = (blockIdx.x << 2) + wid;   // 0..16383

    uint32_t ks2_s = 0x1BD11BF0u;
    asm("" : "+s"(ks2_s));                      // pin for v_add3 (no VOP3 literal)

    const float4* inR = reinterpret_cast<const float4*>(in + (size_t)r * COLS);
    float4 a0 = inR[lane];
    float4 a1 = inR[lane + 64];
    float4 a2 = inR[lane + 128];
    float4 a3 = inR[lane + 192];

    f32x2 a0l = {a0.x, a0.y}, a0h = {a0.z, a0.w};
    f32x2 a1l = {a1.x, a1.y}, a1h = {a1.z, a1.w};
    f32x2 a2l = {a2.x, a2.y}, a2h = {a2.z, a2.w};
    f32x2 a3l = {a3.x, a3.y}, a3h = {a3.z, a3.w};

    const uint32_t base = ((uint32_t)r << 10) + ((uint32_t)lane << 2);

    NoisePair n0 = noise4(base,        ks2_s);
    NoisePair n1 = noise4(base + 256u, ks2_s);
    NoisePair n2 = noise4(base + 512u, ks2_s);
    NoisePair n3 = noise4(base + 768u, ks2_s);

    // packed sum of squares (8 pk_fma instead of 16 scalar)
    f32x2 sa = {0.0f, 0.0f};
    sa = __builtin_elementwise_fma(a0l, a0l, sa);
    sa = __builtin_elementwise_fma(a0h, a0h, sa);
    sa = __builtin_elementwise_fma(a1l, a1l, sa);
    sa = __builtin_elementwise_fma(a1h, a1h, sa);
    sa = __builtin_elementwise_fma(a2l, a2l, sa);
    sa = __builtin_elementwise_fma(a2h, a2h, sa);
    sa = __builtin_elementwise_fma(a3l, a3l, sa);
    sa = __builtin_elementwise_fma(a3h, a3h, sa);
    float ssq = sa.x + sa.y;

    #pragma unroll
    for (int off = 32; off > 0; off >>= 1) {
        ssq += __shfl_xor(ssq, off, 64);
    }

    const float scale = 1.0f / fmaxf(__builtin_amdgcn_sqrtf(ssq), 1.0f);
    const f32x2 sc2 = { scale, scale };

    float4* outR = reinterpret_cast<float4*>(out + (size_t)r * COLS);

    {
        f32x2 ol = __builtin_elementwise_fma(a0l, sc2, n0.lo);
        f32x2 oh = __builtin_elementwise_fma(a0h, sc2, n0.hi);
        float4 o = { ol.x, ol.y, oh.x, oh.y };
        outR[lane] = o;
    }
    {
        f32x2 ol = __builtin_elementwise_fma(a1l, sc2, n1.lo);
        f32x2 oh = __builtin_elementwise_fma(a1h, sc2, n1.hi);
        float4 o = { ol.x, ol.y, oh.x, oh.y };
        outR[lane + 64] = o;
    }
    {
        f32x2 ol = __builtin_elementwise_fma(a2l, sc2, n2.lo);
        f32x2 oh = __builtin_elementwise_fma(a2h, sc2, n2.hi);
        float4 o = { ol.x, ol.y, oh.x, oh.y };
        outR[lane + 128] = o;
    }
    {
        f32x2 ol = __builtin_elementwise_fma(a3l, sc2, n3.lo);
        f32x2 oh = __builtin_elementwise_fma(a3h, sc2, n3.hi);
        float4 o = { ol.x, ol.y, oh.x, oh.y };
        outR[lane + 192] = o;
    }
}

extern "C" void kernel_launch(void* const* d_in, const int* in_sizes, int n_in,
                              void* d_out, int out_size, void* d_ws, size_t ws_size,
                              hipStream_t stream) {
    const float* in = (const float*)d_in[0];
    float* out = (float*)d_out;
    gaussian_dp_kernel<<<ROWS / 4, 256, 0, stream>>>(in, out);
}